// Round 5
// baseline (229.669 us; speedup 1.0000x reference)
//
#include <hip/hip_runtime.h>
#include <math.h>

// YOLO-v1 style loss, S=7, B=2, C=20. Single fused kernel.
// Coalesced float4 stream (exact 5 chunks/thread/array, all 10 loads in
// flight), raw-b128 compact slot staging of box chunks (padded stride),
// per-chunk class SSD in LDS, phase-2 IoU/box losses, block partial ->
// fixed-point u64 atomic (order-independent => deterministic), last block
// writes the scaled scalar. d_ws[0:16) zeroed per call via hipMemsetAsync.
constexpr int NCH  = 30;             // channels per cell
constexpr int CPB  = 128;            // cells per block (64 groups of 2)
constexpr int NT   = 192;            // 3 waves; 960 chunks / 192 = 5 exact
constexpr int NCHK = CPB * NCH / 4;  // 960 float4 chunks per array
constexpr int NIT  = NCHK / NT;      // 5
constexpr int NG   = CPB / 2;        // 64 two-cell groups
constexpr int SLP  = 7;              // pred slot stride (pad 6->7, bank spread)

// Chunk k = f%15 within a 2-cell group (ch0 = 4k mod 30):
//   pred slots: k=0,1,2 -> slot k ; k=7,8,9 -> slot k-4
//   targ slots: k=0,1   -> slot k ; k=7,8   -> slot k-5
//   class elems: k=2(j2,3), k=3..6(all), k=7(j0,1), k=10..14(all)

__global__ __launch_bounds__(NT) void yolo_loss_main(
    const float* __restrict__ pred, const float* __restrict__ targ,
    unsigned long long* __restrict__ acc, unsigned int* __restrict__ cnt,
    float* __restrict__ out, int ncells, double scale)
{
  __shared__ float4 sp4[NG * SLP];    // 7 KB raw pred box chunks (padded)
  __shared__ float4 st4[NG * 4];      // 4 KB raw targ chunks
  __shared__ float  scp[NCHK];        // 3.75 KB per-chunk class SSD
  __shared__ float  swred[NT / 64];

  const int tid = threadIdx.x;
  const int cell0 = blockIdx.x * CPB;
  const int nc = min(CPB, ncells - cell0);
  const size_t base = (size_t)cell0 * NCH;

  float sum = 0.0f;

  if (nc == CPB) {
    const float4* gp = (const float4*)(pred + base);
    const float4* gt = (const float4*)(targ + base);
    float4 pv[NIT], tv[NIT];
    #pragma unroll
    for (int i = 0; i < NIT; ++i) pv[i] = gp[i * NT + tid];
    #pragma unroll
    for (int i = 0; i < NIT; ++i) tv[i] = gt[i * NT + tid];

    int m = tid / 15;                 // one magic-div
    int k = tid - m * 15;
    #pragma unroll
    for (int i = 0; i < NIT; ++i) {
      int ch0 = 4 * k - (k >= 8 ? 30 : 0);
      const float* pf = (const float*)&pv[i];
      const float* tf = (const float*)&tv[i];
      float cp = 0.0f;
      #pragma unroll
      for (int j = 0; j < 4; ++j) {
        int ch = ch0 + j;
        bool cls = (ch >= 10) & (ch < 30);   // wrap (ch>=30) is next-cell box
        float d = pf[j] - tf[j];
        cp += cls ? d * d : 0.0f;
      }
      scp[i * NT + tid] = cp;
      if (k < 3 || (k >= 7 && k <= 9)) sp4[m * SLP + (k < 3 ? k : k - 4)] = pv[i];
      if (k < 2 || k == 7 || k == 8)   st4[m * 4   + (k < 2 ? k : k - 5)] = tv[i];
      // advance f by NT=192: k += 12 (mod 15), m += 12 or 13
      k += 12;
      if (k >= 15) { k -= 15; m += 13; } else { m += 12; }
    }
  } else {
    // tail path (not hit for NB=16384): scalar staging into slot layout
    for (int i = tid; i < NCHK; i += NT) scp[i] = 0.0f;
    float* spf = (float*)sp4;
    float* stf = (float*)st4;
    for (int i = tid; i < nc; i += NT) {
      const float* p = pred + base + (size_t)i * NCH;
      const float* t = targ + base + (size_t)i * NCH;
      int m = i >> 1;
      if ((i & 1) == 0) {
        for (int q = 0; q < 8; ++q) spf[(m * SLP + 0) * 4 + q] = p[q];
        spf[(m * SLP + 2) * 4 + 0] = p[8];
        spf[(m * SLP + 2) * 4 + 1] = p[9];
        for (int q = 0; q < 4; ++q) stf[(m * 4 + 0) * 4 + q] = t[q];
        stf[(m * 4 + 1) * 4 + 0] = t[4];
      } else {
        spf[(m * SLP + 3) * 4 + 2] = p[0];
        spf[(m * SLP + 3) * 4 + 3] = p[1];
        for (int q = 0; q < 8; ++q) spf[(m * SLP + 4) * 4 + q] = p[2 + q];
        stf[(m * 4 + 2) * 4 + 2] = t[0];
        stf[(m * 4 + 2) * 4 + 3] = t[1];
        stf[(m * 4 + 3) * 4 + 0] = t[2];
        stf[(m * 4 + 3) * 4 + 1] = t[3];
        stf[(m * 4 + 3) * 4 + 2] = t[4];
      }
      float o = (t[4] == 1.0f) ? 1.0f : 0.0f;
      float cs = 0.0f;
      for (int q = 10; q < NCH; ++q) { float d = p[q] - t[q]; cs += d * d; }
      sum += o * cs;                   // class folded here; scp stays 0
    }
  }
  __syncthreads();

  // ---- phase 2: per-cell losses ----
  if (tid < nc) {
    int m = tid >> 1;
    bool odd = tid & 1;
    float4 A  = sp4[m * SLP + (odd ? 3 : 0)];
    float4 B  = sp4[m * SLP + (odd ? 4 : 1)];
    float4 Cc = sp4[m * SLP + (odd ? 5 : 2)];
    float px0, py0, pw0, ph0, pc0, px1, py1, pw1, ph1, pc1;
    float tx, ty, tw, th, tobj;
    if (!odd) {
      px0 = A.x;  py0 = A.y;  pw0 = A.z;  ph0 = A.w;
      pc0 = B.x;  px1 = B.y;  py1 = B.z;  pw1 = B.w;
      ph1 = Cc.x; pc1 = Cc.y;
      float4 T0 = st4[m * 4 + 0];
      tx = T0.x; ty = T0.y; tw = T0.z; th = T0.w;
      tobj = st4[m * 4 + 1].x;
    } else {
      px0 = A.z;  py0 = A.w;
      pw0 = B.x;  ph0 = B.y;  pc0 = B.z;  px1 = B.w;
      py1 = Cc.x; pw1 = Cc.y; ph1 = Cc.z; pc1 = Cc.w;
      float4 T2 = st4[m * 4 + 2];
      float4 T3 = st4[m * 4 + 3];
      tx = T2.z; ty = T2.w; tw = T3.x; th = T3.y; tobj = T3.z;
    }
    bool obj = (tobj == 1.0f);

    if (obj) {                         // class loss gather (objf weight)
      const float* cpp = scp + 15 * m;
      float cl;
      if (!odd)
        cl = cpp[2] + cpp[3] + cpp[4] + cpp[5] + cpp[6] + cpp[7];
      else
        cl = cpp[10] + cpp[11] + cpp[12] + cpp[13] + cpp[14];
      sum += cl;
    }

    int cellg = cell0 + tid;
    int rem = cellg % 49;
    int row = rem / 7;
    float fi = (float)row;             // y offset (grid[i][j] = (j, i))
    float fj = (float)(rem - row * 7); // x offset

    float gx = (tx + fj) / 7.0f;
    float gy = (ty + fi) / 7.0f;
    float g1x = gx - 0.5f * tw, g1y = gy - 0.5f * th;
    float g2x = gx + 0.5f * tw, g2y = gy + 0.5f * th;
    float area_g = tw * th;

    float iou0, iou1;
    {
      float cx = (px0 + fj) / 7.0f, cy = (py0 + fi) / 7.0f;
      float wx = fminf(g2x, cx + 0.5f * pw0) - fmaxf(g1x, cx - 0.5f * pw0);
      float wy = fminf(g2y, cy + 0.5f * ph0) - fmaxf(g1y, cy - 0.5f * ph0);
      wx = fmaxf(wx, 0.0f); wy = fmaxf(wy, 0.0f);
      float inter = wx * wy;
      iou0 = inter / (area_g + pw0 * ph0 - inter);
    }
    {
      float cx = (px1 + fj) / 7.0f, cy = (py1 + fi) / 7.0f;
      float wx = fminf(g2x, cx + 0.5f * pw1) - fmaxf(g1x, cx - 0.5f * pw1);
      float wy = fminf(g2y, cy + 0.5f * ph1) - fmaxf(g1y, cy - 0.5f * ph1);
      wx = fmaxf(wx, 0.0f); wy = fmaxf(wy, 0.0f);
      float inter = wx * wy;
      iou1 = inter / (area_g + pw1 * ph1 - inter);
    }

    bool b1 = (iou1 > iou0);           // argmax: ties -> box 0
    float biou = fmaxf(iou0, iou1);

    float lneg = 0.0f;                 // neg_w[b] = obj ? (b != best) : 1
    if (!obj || b1)  lneg += pc0 * pc0;
    if (!obj || !b1) lneg += pc1 * pc1;
    sum += 0.5f * lneg;

    if (obj) {
      float bx = b1 ? px1 : px0;
      float by = b1 ? py1 : py0;
      float bw = b1 ? pw1 : pw0;
      float bh = b1 ? ph1 : ph0;
      float bc = b1 ? pc1 : pc0;
      float dx = bx - tx, dy = by - ty;
      sum += 5.0f * (dx * dx + dy * dy);
      float cw  = fminf(fmaxf(bw, 0.0f), 1.0f);
      float chh = fminf(fmaxf(bh, 0.0f), 1.0f);
      float sw_ = sqrtf(cw)  - sqrtf(tw);
      float sh_ = sqrtf(chh) - sqrtf(th);
      sum += 5.0f * (sw_ * sw_ + sh_ * sh_);
      float dc = bc - biou;
      sum += dc * dc;
    }
  }

  // ---- block reduction -> fixed-point atomic ----
  #pragma unroll
  for (int off = 32; off > 0; off >>= 1) sum += __shfl_down(sum, off);
  if ((tid & 63) == 0) swred[tid >> 6] = sum;
  __syncthreads();
  if (tid == 0) {
    float s = swred[0] + swred[1] + swred[2];
    // quantize to 2^-20 fixed point: integer adds are order-independent
    unsigned long long q = (unsigned long long)((double)s * 1048576.0 + 0.5);
    atomicAdd(acc, q);
    __threadfence();
    unsigned int done = atomicAdd(cnt, 1u);
    if (done == gridDim.x - 1) {       // last block finalizes
      __threadfence();
      unsigned long long a = atomicAdd(acc, 0ull);
      out[0] = (float)((double)a * (1.0 / 1048576.0) * scale);
    }
  }
}

extern "C" void kernel_launch(void* const* d_in, const int* in_sizes, int n_in,
                              void* d_out, int out_size, void* d_ws, size_t ws_size,
                              hipStream_t stream) {
  const float* pred = (const float*)d_in[0];
  const float* targ = (const float*)d_in[1];
  float* out = (float*)d_out;
  unsigned long long* acc = (unsigned long long*)d_ws;
  unsigned int* cnt = (unsigned int*)((char*)d_ws + 8);

  int total = in_sizes[0];             // nb*49*30
  int ncells = total / NCH;
  int nb = ncells / 49;
  int blocks = (ncells + CPB - 1) / CPB;
  double scale = 1.0 / ((double)nb * (double)nb);

  hipMemsetAsync(d_ws, 0, 16, stream); // zero acc+cnt every call (capturable)
  yolo_loss_main<<<blocks, NT, 0, stream>>>(pred, targ, acc, cnt, out,
                                            ncells, scale);
}

// Round 6
// 42.385 us; speedup vs baseline: 5.4186x; 5.4186x over previous
//
#include <hip/hip_runtime.h>
#include <math.h>

// YOLO-v1 style loss, S=7, B=2, C=20. Two kernels (no global atomics —
// R5 showed 6K blocks on one atomic line costs ~190us).
// Coalesced float4 stream (5 chunks/thread/array exact, all 10 loads in
// flight), raw-b128 compact slot staging, per-chunk class SSD in LDS,
// phase-2 IoU/box losses, per-block partial + tiny reduce kernel.
// CPB=128/NT=192: LDS 15.1KB -> 10 blocks/CU (30/32 waves) occupancy probe.
constexpr int NCH  = 30;             // channels per cell
constexpr int CPB  = 128;            // cells per block (64 groups of 2)
constexpr int NT   = 192;            // 3 waves; 960 chunks / 192 = 5 exact
constexpr int NCHK = CPB * NCH / 4;  // 960 float4 chunks per array
constexpr int NIT  = NCHK / NT;      // 5
constexpr int NG   = CPB / 2;        // 64 two-cell groups
constexpr int SLP  = 7;              // pred slot stride (padded)

// Chunk k = f%15 within a 2-cell group (ch0 = 4k mod 30):
//   pred slots: k=0,1,2 -> slot k ; k=7,8,9 -> slot k-4
//   targ slots: k=0,1   -> slot k ; k=7,8   -> slot k-5
//   class elems: k=2(j2,3), k=3..6(all), k=7(j0,1), k=10..14(all)

__global__ __launch_bounds__(NT) void yolo_loss_main(
    const float* __restrict__ pred, const float* __restrict__ targ,
    float* __restrict__ partial, int ncells)
{
  __shared__ float4 sp4[NG * SLP];    // 7 KB raw pred box chunks (padded)
  __shared__ float4 st4[NG * 4];      // 4 KB raw targ chunks
  __shared__ float  scp[NCHK];        // 3.75 KB per-chunk class SSD
  __shared__ float  swred[NT / 64];

  const int tid = threadIdx.x;
  const int cell0 = blockIdx.x * CPB;
  const int nc = min(CPB, ncells - cell0);
  const size_t base = (size_t)cell0 * NCH;

  float sum = 0.0f;

  if (nc == CPB) {
    const float4* gp = (const float4*)(pred + base);
    const float4* gt = (const float4*)(targ + base);
    float4 pv[NIT], tv[NIT];
    #pragma unroll
    for (int i = 0; i < NIT; ++i) pv[i] = gp[i * NT + tid];
    #pragma unroll
    for (int i = 0; i < NIT; ++i) tv[i] = gt[i * NT + tid];

    int m = tid / 15;                 // one magic-div
    int k = tid - m * 15;
    #pragma unroll
    for (int i = 0; i < NIT; ++i) {
      int ch0 = 4 * k - (k >= 8 ? 30 : 0);
      const float* pf = (const float*)&pv[i];
      const float* tf = (const float*)&tv[i];
      float cp = 0.0f;
      #pragma unroll
      for (int j = 0; j < 4; ++j) {
        int ch = ch0 + j;
        bool cls = (ch >= 10) & (ch < 30);   // wrap (ch>=30) is next-cell box
        float d = pf[j] - tf[j];
        cp += cls ? d * d : 0.0f;
      }
      scp[i * NT + tid] = cp;
      if (k < 3 || (k >= 7 && k <= 9)) sp4[m * SLP + (k < 3 ? k : k - 4)] = pv[i];
      if (k < 2 || k == 7 || k == 8)   st4[m * 4   + (k < 2 ? k : k - 5)] = tv[i];
      // advance f by NT=192: k += 12 (mod 15)
      k += 12;
      if (k >= 15) { k -= 15; m += 13; } else { m += 12; }
    }
  } else {
    // tail path (not hit for NB=16384): scalar staging into slot layout
    for (int i = tid; i < NCHK; i += NT) scp[i] = 0.0f;
    float* spf = (float*)sp4;
    float* stf = (float*)st4;
    for (int i = tid; i < nc; i += NT) {
      const float* p = pred + base + (size_t)i * NCH;
      const float* t = targ + base + (size_t)i * NCH;
      int m = i >> 1;
      if ((i & 1) == 0) {
        for (int q = 0; q < 8; ++q) spf[(m * SLP + 0) * 4 + q] = p[q];
        spf[(m * SLP + 2) * 4 + 0] = p[8];
        spf[(m * SLP + 2) * 4 + 1] = p[9];
        for (int q = 0; q < 4; ++q) stf[(m * 4 + 0) * 4 + q] = t[q];
        stf[(m * 4 + 1) * 4 + 0] = t[4];
      } else {
        spf[(m * SLP + 3) * 4 + 2] = p[0];
        spf[(m * SLP + 3) * 4 + 3] = p[1];
        for (int q = 0; q < 8; ++q) spf[(m * SLP + 4) * 4 + q] = p[2 + q];
        stf[(m * 4 + 2) * 4 + 2] = t[0];
        stf[(m * 4 + 2) * 4 + 3] = t[1];
        stf[(m * 4 + 3) * 4 + 0] = t[2];
        stf[(m * 4 + 3) * 4 + 1] = t[3];
        stf[(m * 4 + 3) * 4 + 2] = t[4];
      }
      float o = (t[4] == 1.0f) ? 1.0f : 0.0f;
      float cs = 0.0f;
      for (int q = 10; q < NCH; ++q) { float d = p[q] - t[q]; cs += d * d; }
      sum += o * cs;                   // class folded here; scp stays 0
    }
  }
  __syncthreads();

  // ---- phase 2: per-cell losses ----
  if (tid < nc) {
    int m = tid >> 1;
    bool odd = tid & 1;
    float4 A  = sp4[m * SLP + (odd ? 3 : 0)];
    float4 B  = sp4[m * SLP + (odd ? 4 : 1)];
    float4 Cc = sp4[m * SLP + (odd ? 5 : 2)];
    float px0, py0, pw0, ph0, pc0, px1, py1, pw1, ph1, pc1;
    float tx, ty, tw, th, tobj;
    if (!odd) {
      px0 = A.x;  py0 = A.y;  pw0 = A.z;  ph0 = A.w;
      pc0 = B.x;  px1 = B.y;  py1 = B.z;  pw1 = B.w;
      ph1 = Cc.x; pc1 = Cc.y;
      float4 T0 = st4[m * 4 + 0];
      tx = T0.x; ty = T0.y; tw = T0.z; th = T0.w;
      tobj = st4[m * 4 + 1].x;
    } else {
      px0 = A.z;  py0 = A.w;
      pw0 = B.x;  ph0 = B.y;  pc0 = B.z;  px1 = B.w;
      py1 = Cc.x; pw1 = Cc.y; ph1 = Cc.z; pc1 = Cc.w;
      float4 T2 = st4[m * 4 + 2];
      float4 T3 = st4[m * 4 + 3];
      tx = T2.z; ty = T2.w; tw = T3.x; th = T3.y; tobj = T3.z;
    }
    bool obj = (tobj == 1.0f);

    if (obj) {                         // class loss gather (objf weight)
      const float* cpp = scp + 15 * m;
      float cl;
      if (!odd)
        cl = cpp[2] + cpp[3] + cpp[4] + cpp[5] + cpp[6] + cpp[7];
      else
        cl = cpp[10] + cpp[11] + cpp[12] + cpp[13] + cpp[14];
      sum += cl;
    }

    int cellg = cell0 + tid;
    int rem = cellg % 49;
    int row = rem / 7;
    float fi = (float)row;             // y offset (grid[i][j] = (j, i))
    float fj = (float)(rem - row * 7); // x offset

    float gx = (tx + fj) / 7.0f;
    float gy = (ty + fi) / 7.0f;
    float g1x = gx - 0.5f * tw, g1y = gy - 0.5f * th;
    float g2x = gx + 0.5f * tw, g2y = gy + 0.5f * th;
    float area_g = tw * th;

    float iou0, iou1;
    {
      float cx = (px0 + fj) / 7.0f, cy = (py0 + fi) / 7.0f;
      float wx = fminf(g2x, cx + 0.5f * pw0) - fmaxf(g1x, cx - 0.5f * pw0);
      float wy = fminf(g2y, cy + 0.5f * ph0) - fmaxf(g1y, cy - 0.5f * ph0);
      wx = fmaxf(wx, 0.0f); wy = fmaxf(wy, 0.0f);
      float inter = wx * wy;
      iou0 = inter / (area_g + pw0 * ph0 - inter);
    }
    {
      float cx = (px1 + fj) / 7.0f, cy = (py1 + fi) / 7.0f;
      float wx = fminf(g2x, cx + 0.5f * pw1) - fmaxf(g1x, cx - 0.5f * pw1);
      float wy = fminf(g2y, cy + 0.5f * ph1) - fmaxf(g1y, cy - 0.5f * ph1);
      wx = fmaxf(wx, 0.0f); wy = fmaxf(wy, 0.0f);
      float inter = wx * wy;
      iou1 = inter / (area_g + pw1 * ph1 - inter);
    }

    bool b1 = (iou1 > iou0);           // argmax: ties -> box 0
    float biou = fmaxf(iou0, iou1);

    float lneg = 0.0f;                 // neg_w[b] = obj ? (b != best) : 1
    if (!obj || b1)  lneg += pc0 * pc0;
    if (!obj || !b1) lneg += pc1 * pc1;
    sum += 0.5f * lneg;

    if (obj) {
      float bx = b1 ? px1 : px0;
      float by = b1 ? py1 : py0;
      float bw = b1 ? pw1 : pw0;
      float bh = b1 ? ph1 : ph0;
      float bc = b1 ? pc1 : pc0;
      float dx = bx - tx, dy = by - ty;
      sum += 5.0f * (dx * dx + dy * dy);
      float cw  = fminf(fmaxf(bw, 0.0f), 1.0f);
      float chh = fminf(fmaxf(bh, 0.0f), 1.0f);
      float sw_ = sqrtf(cw)  - sqrtf(tw);
      float sh_ = sqrtf(chh) - sqrtf(th);
      sum += 5.0f * (sw_ * sw_ + sh_ * sh_);
      float dc = bc - biou;
      sum += dc * dc;
    }
  }

  // ---- block reduction ----
  #pragma unroll
  for (int off = 32; off > 0; off >>= 1) sum += __shfl_down(sum, off);
  if ((tid & 63) == 0) swred[tid >> 6] = sum;
  __syncthreads();
  if (tid == 0)
    partial[blockIdx.x] = swred[0] + swred[1] + swred[2];
}

__global__ __launch_bounds__(256) void yolo_loss_reduce(
    const float* __restrict__ partial, int n, float* __restrict__ out,
    float scale)
{
  __shared__ float swred[4];
  float s = 0.0f;
  for (int i = threadIdx.x; i < n; i += 256) s += partial[i];
  #pragma unroll
  for (int off = 32; off > 0; off >>= 1) s += __shfl_down(s, off);
  if ((threadIdx.x & 63) == 0) swred[threadIdx.x >> 6] = s;
  __syncthreads();
  if (threadIdx.x == 0)
    out[0] = (swred[0] + swred[1] + swred[2] + swred[3]) * scale;
}

extern "C" void kernel_launch(void* const* d_in, const int* in_sizes, int n_in,
                              void* d_out, int out_size, void* d_ws, size_t ws_size,
                              hipStream_t stream) {
  const float* pred = (const float*)d_in[0];
  const float* targ = (const float*)d_in[1];
  float* out = (float*)d_out;
  float* partial = (float*)d_ws;

  int total = in_sizes[0];             // nb*49*30
  int ncells = total / NCH;
  int nb = ncells / 49;
  int blocks = (ncells + CPB - 1) / CPB;
  float scale = 1.0f / ((float)nb * (float)nb);

  yolo_loss_main<<<blocks, NT, 0, stream>>>(pred, targ, partial, ncells);
  yolo_loss_reduce<<<1, 256, 0, stream>>>(partial, blocks, out, scale);
}

// Round 7
// 38.900 us; speedup vs baseline: 5.9041x; 1.0896x over previous
//
#include <hip/hip_runtime.h>
#include <math.h>

// YOLO-v1 style loss, S=7, B=2, C=20.
// Best-measured config (R4, 39.1us): near-pure coalesced float4 stream,
// exact 6 chunks/thread (NT=320), register-batched loads (3+3 in flight),
// raw-b128 compact slot staging of box chunks, per-chunk class SSD into LDS,
// phase-2 unpack + IoU/box losses. Two kernels (R5 showed grid-wide atomics
// on one line cost ~190us). Occupancy sweep (R1-R6) showed 46% occ is NOT
// the limiter; effective L3-read rate ~4.95 TB/s is the plateau.
constexpr int NCH  = 30;             // channels per cell
constexpr int CPB  = 256;            // cells per block (128 groups of 2)
constexpr int NT   = 320;            // 5 waves; 1920 chunks / 320 = 6 exact
constexpr int NCHK = CPB * NCH / 4;  // 1920 float4 chunks per block per array
constexpr int NIT  = NCHK / NT;      // 6

// Chunk k = f%15 within a 2-cell group (ch0 = 4k mod 30):
//   pred box slots: k=0,1,2 -> slot k   (even cell ch0-3,4-7,8-9)
//                   k=7,8,9 -> slot k-4 (odd  cell ch0-1(wrap),2-5,6-9)
//   targ slots:     k=0,1   -> slot k   (even ch0-3, ch4)
//                   k=7,8   -> slot k-5 (odd  ch0-1(wrap), ch2-4)
//   class elems: k=2 (j2,3), k=3..6 (all), k=7 (j0,1), k=10..14 (all)

__global__ __launch_bounds__(NT) void yolo_loss_main(
    const float* __restrict__ pred, const float* __restrict__ targ,
    float* __restrict__ partial, int ncells)
{
  __shared__ float4 sp4[(CPB / 2) * 6];   // 12 KB raw pred box chunks
  __shared__ float4 st4[(CPB / 2) * 4];   //  8 KB raw targ chunks
  __shared__ float  scp[NCHK];            // 7.5 KB per-chunk class SSD
  __shared__ float  swred[NT / 64];

  const int tid = threadIdx.x;
  const int cell0 = blockIdx.x * CPB;
  const int nc = min(CPB, ncells - cell0);
  const size_t base = (size_t)cell0 * NCH;

  float sum = 0.0f;

  if (nc == CPB) {
    const float4* gp = (const float4*)(pred + base);
    const float4* gt = (const float4*)(targ + base);

    #pragma unroll
    for (int b = 0; b < 2; ++b) {          // two batches of 3 chunks
      float4 pv[3], tv[3];
      #pragma unroll
      for (int i = 0; i < 3; ++i) pv[i] = gp[(3 * b + i) * NT + tid];
      #pragma unroll
      for (int i = 0; i < 3; ++i) tv[i] = gt[(3 * b + i) * NT + tid];

      #pragma unroll
      for (int i = 0; i < 3; ++i) {
        int f = (3 * b + i) * NT + tid;
        int m = f / 15;                    // magic-mul
        int k = f - m * 15;
        int ch0 = 4 * k - (k >= 8 ? 30 : 0);

        float cp = 0.0f;
        #pragma unroll
        for (int j = 0; j < 4; ++j) {
          int ch = ch0 + j;
          bool cls = (ch >= 10) & (ch < 30);   // wrap (ch>=30) is box
          float d = ((const float*)&pv[i])[j] - ((const float*)&tv[i])[j];
          cp += cls ? d * d : 0.0f;
        }
        scp[f] = cp;

        if (k < 3 || (k >= 7 && k <= 9)) {
          int ps = (k < 3) ? k : (k - 4);
          sp4[m * 6 + ps] = pv[i];
        }
        if (k < 2 || k == 7 || k == 8) {
          int ts = (k < 2) ? k : (k - 5);
          st4[m * 4 + ts] = tv[i];
        }
      }
    }
  } else {
    // tail path (not hit for NB=16384): scalar staging into slot layout
    for (int i = tid; i < NCHK; i += NT) scp[i] = 0.0f;
    float* spf = (float*)sp4;
    float* stf = (float*)st4;
    for (int i = tid; i < nc; i += NT) {
      const float* p = pred + base + (size_t)i * NCH;
      const float* t = targ + base + (size_t)i * NCH;
      int m = i >> 1;
      if ((i & 1) == 0) {
        for (int q = 0; q < 8; ++q) spf[(m * 6 + 0) * 4 + q] = p[q];
        spf[(m * 6 + 2) * 4 + 0] = p[8];
        spf[(m * 6 + 2) * 4 + 1] = p[9];
        for (int q = 0; q < 4; ++q) stf[(m * 4 + 0) * 4 + q] = t[q];
        stf[(m * 4 + 1) * 4 + 0] = t[4];
      } else {
        spf[(m * 6 + 3) * 4 + 2] = p[0];
        spf[(m * 6 + 3) * 4 + 3] = p[1];
        for (int q = 0; q < 8; ++q) spf[(m * 6 + 4) * 4 + q] = p[2 + q];
        stf[(m * 4 + 2) * 4 + 2] = t[0];
        stf[(m * 4 + 2) * 4 + 3] = t[1];
        stf[(m * 4 + 3) * 4 + 0] = t[2];
        stf[(m * 4 + 3) * 4 + 1] = t[3];
        stf[(m * 4 + 3) * 4 + 2] = t[4];
      }
      float o = (t[4] == 1.0f) ? 1.0f : 0.0f;
      float cs = 0.0f;
      for (int q = 10; q < NCH; ++q) { float d = p[q] - t[q]; cs += d * d; }
      sum += o * cs;                       // class handled here; scp stays 0
    }
  }
  __syncthreads();

  // ---- phase 2: per-cell losses ----
  if (tid < nc) {
    int m = tid >> 1;
    bool odd = tid & 1;
    float4 A = sp4[m * 6 + (odd ? 3 : 0)];
    float4 B = sp4[m * 6 + (odd ? 4 : 1)];
    float4 Cc = sp4[m * 6 + (odd ? 5 : 2)];
    float px0, py0, pw0, ph0, pc0, px1, py1, pw1, ph1, pc1;
    float tx, ty, tw, th, tobj;
    if (!odd) {
      px0 = A.x;  py0 = A.y;  pw0 = A.z;  ph0 = A.w;
      pc0 = B.x;  px1 = B.y;  py1 = B.z;  pw1 = B.w;
      ph1 = Cc.x; pc1 = Cc.y;
      float4 T0 = st4[m * 4 + 0];
      tx = T0.x; ty = T0.y; tw = T0.z; th = T0.w;
      tobj = st4[m * 4 + 1].x;
    } else {
      px0 = A.z;  py0 = A.w;
      pw0 = B.x;  ph0 = B.y;  pc0 = B.z;  px1 = B.w;
      py1 = Cc.x; pw1 = Cc.y; ph1 = Cc.z; pc1 = Cc.w;
      float4 T2 = st4[m * 4 + 2];
      float4 T3 = st4[m * 4 + 3];
      tx = T2.z; ty = T2.w; tw = T3.x; th = T3.y; tobj = T3.z;
    }
    bool obj = (tobj == 1.0f);

    // class loss: gather this cell's chunk partials, weight by objf
    if (obj) {
      const float* cpp = scp + 15 * m;
      float cl;
      if (!odd)
        cl = cpp[2] + cpp[3] + cpp[4] + cpp[5] + cpp[6] + cpp[7];
      else
        cl = cpp[10] + cpp[11] + cpp[12] + cpp[13] + cpp[14];
      sum += cl;
    }

    int cellg = cell0 + tid;
    int rem = cellg % 49;
    int row = rem / 7;
    float fi = (float)row;              // y offset (grid[i][j] = (j, i))
    float fj = (float)(rem - row * 7);  // x offset

    float gx = (tx + fj) / 7.0f;
    float gy = (ty + fi) / 7.0f;
    float g1x = gx - 0.5f * tw, g1y = gy - 0.5f * th;
    float g2x = gx + 0.5f * tw, g2y = gy + 0.5f * th;
    float area_g = tw * th;

    float iou0, iou1;
    {
      float cx = (px0 + fj) / 7.0f, cy = (py0 + fi) / 7.0f;
      float wx = fminf(g2x, cx + 0.5f * pw0) - fmaxf(g1x, cx - 0.5f * pw0);
      float wy = fminf(g2y, cy + 0.5f * ph0) - fmaxf(g1y, cy - 0.5f * ph0);
      wx = fmaxf(wx, 0.0f); wy = fmaxf(wy, 0.0f);
      float inter = wx * wy;
      iou0 = inter / (area_g + pw0 * ph0 - inter);
    }
    {
      float cx = (px1 + fj) / 7.0f, cy = (py1 + fi) / 7.0f;
      float wx = fminf(g2x, cx + 0.5f * pw1) - fmaxf(g1x, cx - 0.5f * pw1);
      float wy = fminf(g2y, cy + 0.5f * ph1) - fmaxf(g1y, cy - 0.5f * ph1);
      wx = fmaxf(wx, 0.0f); wy = fmaxf(wy, 0.0f);
      float inter = wx * wy;
      iou1 = inter / (area_g + pw1 * ph1 - inter);
    }

    bool b1 = (iou1 > iou0);            // argmax: ties -> box 0
    float biou = fmaxf(iou0, iou1);

    // negative-confidence loss: neg_w[b] = obj ? (b != best) : 1
    float lneg = 0.0f;
    if (!obj || b1)  lneg += pc0 * pc0;
    if (!obj || !b1) lneg += pc1 * pc1;
    sum += 0.5f * lneg;

    if (obj) {
      float bx = b1 ? px1 : px0;
      float by = b1 ? py1 : py0;
      float bw = b1 ? pw1 : pw0;
      float bh = b1 ? ph1 : ph0;
      float bc = b1 ? pc1 : pc0;
      float dx = bx - tx, dy = by - ty;
      sum += 5.0f * (dx * dx + dy * dy);
      float cw  = fminf(fmaxf(bw, 0.0f), 1.0f);
      float chh = fminf(fmaxf(bh, 0.0f), 1.0f);
      float sw_ = sqrtf(cw)  - sqrtf(tw);
      float sh_ = sqrtf(chh) - sqrtf(th);
      sum += 5.0f * (sw_ * sw_ + sh_ * sh_);
      float dc = bc - biou;
      sum += dc * dc;
    }
  }

  // ---- block reduction ----
  #pragma unroll
  for (int off = 32; off > 0; off >>= 1) sum += __shfl_down(sum, off);
  if ((tid & 63) == 0) swred[tid >> 6] = sum;
  __syncthreads();
  if (tid == 0) {
    float s = 0.0f;
    #pragma unroll
    for (int w = 0; w < NT / 64; ++w) s += swred[w];
    partial[blockIdx.x] = s;
  }
}

__global__ __launch_bounds__(256) void yolo_loss_reduce(
    const float* __restrict__ partial, int n, float* __restrict__ out,
    float scale)
{
  __shared__ float swred[4];
  float s = 0.0f;
  for (int i = threadIdx.x; i < n; i += 256) s += partial[i];
  #pragma unroll
  for (int off = 32; off > 0; off >>= 1) s += __shfl_down(s, off);
  if ((threadIdx.x & 63) == 0) swred[threadIdx.x >> 6] = s;
  __syncthreads();
  if (threadIdx.x == 0)
    out[0] = (swred[0] + swred[1] + swred[2] + swred[3]) * scale;
}

extern "C" void kernel_launch(void* const* d_in, const int* in_sizes, int n_in,
                              void* d_out, int out_size, void* d_ws, size_t ws_size,
                              hipStream_t stream) {
  const float* pred = (const float*)d_in[0];
  const float* targ = (const float*)d_in[1];
  float* out = (float*)d_out;
  float* partial = (float*)d_ws;

  int total = in_sizes[0];             // nb*49*30
  int ncells = total / NCH;
  int nb = ncells / 49;
  int blocks = (ncells + CPB - 1) / CPB;
  float scale = 1.0f / ((float)nb * (float)nb);

  yolo_loss_main<<<blocks, NT, 0, stream>>>(pred, targ, partial, ncells);
  yolo_loss_reduce<<<1, 256, 0, stream>>>(partial, blocks, out, scale);
}